// Round 2
// baseline (686.202 us; speedup 1.0000x reference)
//
#include <hip/hip_runtime.h>

#define N_NODES 20000
#define E_EDGES 320000
#define IN_DIM_C 896
#define HIDDEN_C 256

__device__ __forceinline__ float lrelu(float v){ return v > 0.f ? v : 0.2f * v; }

// ---------------- CSR build ----------------
__global__ __launch_bounds__(256) void k_count(const int* __restrict__ dst, int* __restrict__ deg, int E){
  int e = blockIdx.x * 256 + threadIdx.x;
  if (e < E) atomicAdd(&deg[dst[e]], 1);
}

__global__ __launch_bounds__(256) void k_scan(const int* __restrict__ deg, int* __restrict__ off,
                                              int* __restrict__ cur, int n){
  __shared__ int part[256];
  __shared__ int base[257];
  int tid = threadIdx.x;
  int chunk = (n + 255) / 256;
  int st = tid * chunk;
  int en = st + chunk; if (en > n) en = n;
  int s = 0;
  for (int i = st; i < en; ++i) s += deg[i];
  part[tid] = s;
  __syncthreads();
  if (tid == 0){
    int a = 0;
    for (int i = 0; i < 256; ++i){ base[i] = a; a += part[i]; }
    base[256] = a;
  }
  __syncthreads();
  int a = base[tid];
  for (int i = st; i < en; ++i){ off[i] = a; cur[i] = 0; a += deg[i]; }
  if (tid == 0) off[n] = base[256];
}

__global__ __launch_bounds__(256) void k_fill(const int* __restrict__ src, const int* __restrict__ dst,
                       const int* __restrict__ ety, const float* __restrict__ ew,
                       const int* __restrict__ off, int* __restrict__ cur,
                       int* __restrict__ csrc, int* __restrict__ cet, float* __restrict__ cw, int E){
  int e = blockIdx.x * 256 + threadIdx.x;
  if (e < E){
    int d = dst[e];
    int p = atomicAdd(&cur[d], 1);
    int i = off[d] + p;
    csrc[i] = src[e];
    cet[i]  = ety[e];
    cw[i]   = ew[e];
  }
}

// ---------------- GEMM: C[M][256] = A[M][K] @ B[K][256] (+bias,relu) (+att epilogue) ----
// PERM: A is x (f32, row K=896) with xc permutation: c<128 -> col 768+c; else 3*col(c-128)
// EPI:  add bias + relu.  ATT: also produce a_src/a_dst per (row, head).
template<bool PERM, bool EPI, bool ATT>
__global__ __launch_bounds__(256) void k_gemm(
    const float* __restrict__ A, const float* __restrict__ B,
    const float* __restrict__ bias, float* __restrict__ C,
    const float* __restrict__ attS, const float* __restrict__ attD,
    float* __restrict__ aS, float* __restrict__ aD,
    int M, int K)
{
  __shared__ float As[64][33];
  __shared__ float Bs[32][256];
  const int tid  = threadIdx.x;
  const int lane = tid & 63;
  const int wid  = tid >> 6;
  const int c0   = lane * 4;       // this thread's 4 output columns
  const int r0   = wid * 16;       // this wave's 16 output rows
  const int m0   = blockIdx.x * 64;

  float4 acc[16];
#pragma unroll
  for (int i = 0; i < 16; ++i) acc[i] = make_float4(0.f, 0.f, 0.f, 0.f);

  const int arow = tid >> 2;          // 0..63
  const int akk  = (tid & 3) * 8;     // 0,8,16,24
  const int brow = tid >> 3;          // 0..31
  const int bnn  = (tid & 7) * 32;    // 0..224
  const int gr   = m0 + arow;

  for (int k0 = 0; k0 < K; k0 += 32){
    // --- stage A tile (apply permutation/scale for PERM) ---
    float av[8];
    if (gr < M){
      if constexpr (PERM){
        int c = k0 + akk;               // 8-chunks never straddle c=128
        const float* sp; float sc;
        if (c < 128){ sp = A + (size_t)gr * 896 + (768 + c); sc = 1.f; }
        else        { sp = A + (size_t)gr * 896 + (c - 128); sc = 3.f; }
        float4 f0 = *(const float4*)sp;
        float4 f1 = *(const float4*)(sp + 4);
        av[0]=f0.x*sc; av[1]=f0.y*sc; av[2]=f0.z*sc; av[3]=f0.w*sc;
        av[4]=f1.x*sc; av[5]=f1.y*sc; av[6]=f1.z*sc; av[7]=f1.w*sc;
      } else {
        const float* sp = A + (size_t)gr * K + k0 + akk;
        float4 f0 = *(const float4*)sp;
        float4 f1 = *(const float4*)(sp + 4);
        av[0]=f0.x; av[1]=f0.y; av[2]=f0.z; av[3]=f0.w;
        av[4]=f1.x; av[5]=f1.y; av[6]=f1.z; av[7]=f1.w;
      }
    } else {
#pragma unroll
      for (int j = 0; j < 8; ++j) av[j] = 0.f;
    }
#pragma unroll
    for (int j = 0; j < 8; ++j) As[arow][akk + j] = av[j];

    // --- stage B tile ---
    {
      const float* bp2 = B + (size_t)(k0 + brow) * 256 + bnn;
#pragma unroll
      for (int j = 0; j < 32; j += 4)
        *(float4*)&Bs[brow][bnn + j] = *(const float4*)(bp2 + j);
    }
    __syncthreads();
#pragma unroll
    for (int k = 0; k < 32; ++k){
      float4 b = *(const float4*)&Bs[k][c0];
#pragma unroll
      for (int r = 0; r < 16; ++r){
        float a = As[r0 + r][k];            // broadcast across wave
        acc[r].x = fmaf(a, b.x, acc[r].x);
        acc[r].y = fmaf(a, b.y, acc[r].y);
        acc[r].z = fmaf(a, b.z, acc[r].z);
        acc[r].w = fmaf(a, b.w, acc[r].w);
      }
    }
    __syncthreads();
  }

  if constexpr (EPI){
    float4 bb = *(const float4*)&bias[c0];
#pragma unroll
    for (int r = 0; r < 16; ++r){
      int g = m0 + r0 + r;
      if (g < M){
        float4 v;
        v.x = fmaxf(acc[r].x + bb.x, 0.f);
        v.y = fmaxf(acc[r].y + bb.y, 0.f);
        v.z = fmaxf(acc[r].z + bb.z, 0.f);
        v.w = fmaxf(acc[r].w + bb.w, 0.f);
        *(float4*)&C[(size_t)g * 256 + c0] = v;
      }
    }
  } else {
#pragma unroll
    for (int r = 0; r < 16; ++r){
      int g = m0 + r0 + r;
      if (g < M) *(float4*)&C[(size_t)g * 256 + c0] = acc[r];
    }
  }

  if constexpr (ATT){
    // a_src[n][h] = sum_ch xh[n][h*64+ch] * attS[h*64+ch]; flat index == c0
    float4 sv = *(const float4*)&attS[c0];
    float4 dv = *(const float4*)&attD[c0];
#pragma unroll
    for (int r = 0; r < 16; ++r){
      float ps = acc[r].x*sv.x + acc[r].y*sv.y + acc[r].z*sv.z + acc[r].w*sv.w;
      float pd = acc[r].x*dv.x + acc[r].y*dv.y + acc[r].z*dv.z + acc[r].w*dv.w;
#pragma unroll
      for (int mm = 1; mm < 16; mm <<= 1){
        ps += __shfl_xor(ps, mm, 64);
        pd += __shfl_xor(pd, mm, 64);
      }
      int g = m0 + r0 + r;
      if ((lane & 15) == 0 && g < M){
        int head = lane >> 4;
        aS[(size_t)g * 4 + head] = ps;
        aD[(size_t)g * 4 + head] = pd;
      }
    }
  }
}

// ---------------- first aggregation: h1 = h0 + sum_e (h0[src] + rel[et]*w) ----------------
__global__ __launch_bounds__(256) void k_agg(
    const float* __restrict__ h0, const int* __restrict__ off,
    const int* __restrict__ csrc, const int* __restrict__ cet, const float* __restrict__ cw,
    const float* __restrict__ rel, float* __restrict__ h1, int N)
{
  int n = blockIdx.x * 4 + (threadIdx.x >> 6);
  if (n >= N) return;
  int lane = threadIdx.x & 63;
  int c0 = lane * 4;
  float4 acc = *(const float4*)&h0[(size_t)n * 256 + c0];
  int s0 = off[n], s1 = off[n + 1];
  for (int e = s0; e < s1; ++e){
    int s   = csrc[e];
    int t   = cet[e];
    float wg = cw[e];
    float4 hv = *(const float4*)&h0[(size_t)s * 256 + c0];
    float4 rv = *(const float4*)&rel[(size_t)t * 256 + c0];
    acc.x += hv.x + rv.x * wg;
    acc.y += hv.y + rv.y * wg;
    acc.z += hv.z + rv.z * wg;
    acc.w += hv.w + rv.w * wg;
  }
  *(float4*)&h1[(size_t)n * 256 + c0] = acc;
}

// ---------------- GAT edge softmax + aggregate (self-loop included) ----------------
__global__ __launch_bounds__(256) void k_gat(
    const float* __restrict__ xh, const float* __restrict__ aS, const float* __restrict__ aD,
    const int* __restrict__ off, const int* __restrict__ csrc,
    const float* __restrict__ bias, float* __restrict__ hout, int N)
{
  int n = blockIdx.x * 4 + (threadIdx.x >> 6);
  if (n >= N) return;
  int lane = threadIdx.x & 63;
  int head = lane >> 4;
  int c0 = lane * 4;
  int s0 = off[n], s1 = off[n + 1];

  float ad0, ad1, ad2, ad3;
  { float4 t = *(const float4*)&aD[(size_t)n * 4]; ad0 = t.x; ad1 = t.y; ad2 = t.z; ad3 = t.w; }
  float q0, q1, q2, q3;  // running max per head (init with self-loop)
  { float4 t = *(const float4*)&aS[(size_t)n * 4];
    q0 = lrelu(t.x + ad0); q1 = lrelu(t.y + ad1); q2 = lrelu(t.z + ad2); q3 = lrelu(t.w + ad3); }

  // pass 1: max (lane-parallel over edges)
  for (int base = s0; base < s1; base += 64){
    int e = base + lane;
    if (e < s1){
      int s = csrc[e];
      float4 av = *(const float4*)&aS[(size_t)s * 4];
      q0 = fmaxf(q0, lrelu(av.x + ad0));
      q1 = fmaxf(q1, lrelu(av.y + ad1));
      q2 = fmaxf(q2, lrelu(av.z + ad2));
      q3 = fmaxf(q3, lrelu(av.w + ad3));
    }
  }
#pragma unroll
  for (int mm = 1; mm < 64; mm <<= 1){
    q0 = fmaxf(q0, __shfl_xor(q0, mm, 64));
    q1 = fmaxf(q1, __shfl_xor(q1, mm, 64));
    q2 = fmaxf(q2, __shfl_xor(q2, mm, 64));
    q3 = fmaxf(q3, __shfl_xor(q3, mm, 64));
  }
  float adh = head == 0 ? ad0 : (head == 1 ? ad1 : (head == 2 ? ad2 : ad3));
  float mh  = head == 0 ? q0  : (head == 1 ? q1  : (head == 2 ? q2  : q3));

  // pass 2: exp + accumulate (wave-parallel over channels, serial over edges)
  float ash = aS[(size_t)n * 4 + head];
  float ex = __expf(lrelu(ash + adh) - mh);
  float den = ex;
  float4 xv = *(const float4*)&xh[(size_t)n * 256 + c0];
  float4 acc;
  acc.x = ex * xv.x; acc.y = ex * xv.y; acc.z = ex * xv.z; acc.w = ex * xv.w;
  for (int e = s0; e < s1; ++e){
    int s = csrc[e];
    float a  = aS[(size_t)s * 4 + head];
    float e2 = __expf(lrelu(a + adh) - mh);
    den += e2;
    float4 x2 = *(const float4*)&xh[(size_t)s * 256 + c0];
    acc.x = fmaf(e2, x2.x, acc.x);
    acc.y = fmaf(e2, x2.y, acc.y);
    acc.z = fmaf(e2, x2.z, acc.z);
    acc.w = fmaf(e2, x2.w, acc.w);
  }
  float inv = 1.f / den;
  float4 bb = *(const float4*)&bias[c0];
  float4 o;
  o.x = acc.x * inv + bb.x;
  o.y = acc.y * inv + bb.y;
  o.z = acc.z * inv + bb.z;
  o.w = acc.w * inv + bb.w;
  *(float4*)&hout[(size_t)n * 256 + c0] = o;
}

// ---------------- final score ----------------
__global__ __launch_bounds__(256) void k_score(
    const float* __restrict__ h, const float* __restrict__ Wo, const float* __restrict__ bo,
    float* __restrict__ out, int N)
{
  int n = blockIdx.x * 4 + (threadIdx.x >> 6);
  if (n >= N) return;
  int lane = threadIdx.x & 63;
  int c0 = lane * 4;
  float4 hv = *(const float4*)&h[(size_t)n * 256 + c0];
  float4 wv = *(const float4*)&Wo[c0];
  float p = hv.x * wv.x + hv.y * wv.y + hv.z * wv.z + hv.w * wv.w;
#pragma unroll
  for (int mm = 1; mm < 64; mm <<= 1) p += __shfl_xor(p, mm, 64);
  if (lane == 0) out[n] = p + bo[0];
}

extern "C" void kernel_launch(void* const* d_in, const int* in_sizes, int n_in,
                              void* d_out, int out_size, void* d_ws, size_t ws_size,
                              hipStream_t stream)
{
  const float* x   = (const float*)d_in[0];
  const int*   ei  = (const int*)  d_in[1];
  const int*   ety = (const int*)  d_in[2];
  const float* ew  = (const float*)d_in[3];
  const float* rel = (const float*)d_in[4];
  const float* Wp  = (const float*)d_in[5];
  const float* bp  = (const float*)d_in[6];
  const float* W1  = (const float*)d_in[7];
  const float* as1 = (const float*)d_in[8];
  const float* ad1 = (const float*)d_in[9];
  const float* b1  = (const float*)d_in[10];
  const float* W2  = (const float*)d_in[11];
  const float* as2 = (const float*)d_in[12];
  const float* ad2 = (const float*)d_in[13];
  const float* b2  = (const float*)d_in[14];
  const float* Wo  = (const float*)d_in[15];
  const float* bo  = (const float*)d_in[16];
  float* out = (float*)d_out;

  const int N = N_NODES, E = E_EDGES;
  char* w = (char*)d_ws;
  size_t o = 0;
  auto alloc = [&](size_t bytes) -> char* {
    char* p = w + o;
    o = (o + bytes + 255) & ~(size_t)255;
    return p;
  };
  float* h0  = (float*)alloc((size_t)N * 256 * 4);
  float* h1  = (float*)alloc((size_t)N * 256 * 4);
  float* xh  = (float*)alloc((size_t)N * 256 * 4);
  float* aS  = (float*)alloc((size_t)N * 4 * 4);
  float* aD  = (float*)alloc((size_t)N * 4 * 4);
  int* deg   = (int*)alloc((size_t)N * 4);
  int* offs  = (int*)alloc((size_t)(N + 1) * 4);
  int* cur   = (int*)alloc((size_t)N * 4);
  int* csrc  = (int*)alloc((size_t)E * 4);
  int* cet   = (int*)alloc((size_t)E * 4);
  float* cw  = (float*)alloc((size_t)E * 4);

  const int* srcp = ei;
  const int* dstp = ei + E;

  hipMemsetAsync(deg, 0, (size_t)N * 4, stream);
  k_count<<<(E + 255) / 256, 256, 0, stream>>>(dstp, deg, E);
  k_scan<<<1, 256, 0, stream>>>(deg, offs, cur, N);
  k_fill<<<(E + 255) / 256, 256, 0, stream>>>(srcp, dstp, ety, ew, offs, cur, csrc, cet, cw, E);

  int gblk = (N + 63) / 64;
  int nblk = (N + 3) / 4;
  // h0 = relu(xc @ Wp + bp)
  k_gemm<true, true, false><<<gblk, 256, 0, stream>>>(
      x, Wp, bp, h0, nullptr, nullptr, nullptr, nullptr, N, IN_DIM_C);
  // h1 = h0 + sum_in(h0[src] + rel*w)
  k_agg<<<nblk, 256, 0, stream>>>(h0, offs, csrc, cet, cw, rel, h1, N);
  // GAT layer 1
  k_gemm<false, false, true><<<gblk, 256, 0, stream>>>(
      h1, W1, nullptr, xh, as1, ad1, aS, aD, N, HIDDEN_C);
  k_gat<<<nblk, 256, 0, stream>>>(xh, aS, aD, offs, csrc, b1, h1, N);
  // GAT layer 2
  k_gemm<false, false, true><<<gblk, 256, 0, stream>>>(
      h1, W2, nullptr, xh, as2, ad2, aS, aD, N, HIDDEN_C);
  k_gat<<<nblk, 256, 0, stream>>>(xh, aS, aD, offs, csrc, b2, h1, N);
  // score
  k_score<<<nblk, 256, 0, stream>>>(h1, Wo, bo, out, N);
}

// Round 3
// 359.641 us; speedup vs baseline: 1.9080x; 1.9080x over previous
//
#include <hip/hip_runtime.h>

#define N_NODES 20000
#define E_EDGES 320000
#define HIDDEN_C 256

typedef __attribute__((ext_vector_type(8))) short s8v;
typedef __attribute__((ext_vector_type(4))) float f4v;

__device__ __forceinline__ float lrelu(float v){ return v > 0.f ? v : 0.2f * v; }

// round-to-nearest-even f32 -> bf16 (bit trick)
__device__ __forceinline__ unsigned short bfhi(float v){
  union{float f; unsigned u;} a; a.f = v;
  unsigned r = a.u + 0x7FFFu + ((a.u >> 16) & 1u);
  return (unsigned short)(r >> 16);
}
__device__ __forceinline__ float bf2f(unsigned short h){
  union{unsigned u; float f;} a; a.u = ((unsigned)h) << 16; return a.f;
}

// ---------------- CSR build ----------------
__global__ __launch_bounds__(256) void k_count(const int* __restrict__ dst, int* __restrict__ deg, int E){
  int e = blockIdx.x * 256 + threadIdx.x;
  if (e < E) atomicAdd(&deg[dst[e]], 1);
}

__global__ __launch_bounds__(256) void k_scan(const int* __restrict__ deg, int* __restrict__ off,
                                              int* __restrict__ cur, int n){
  __shared__ int part[256];
  __shared__ int base[257];
  int tid = threadIdx.x;
  int chunk = (n + 255) / 256;
  int st = tid * chunk;
  int en = st + chunk; if (en > n) en = n;
  int s = 0;
  for (int i = st; i < en; ++i) s += deg[i];
  part[tid] = s;
  __syncthreads();
  if (tid == 0){
    int a = 0;
    for (int i = 0; i < 256; ++i){ base[i] = a; a += part[i]; }
    base[256] = a;
  }
  __syncthreads();
  int a = base[tid];
  for (int i = st; i < en; ++i){ off[i] = a; cur[i] = 0; a += deg[i]; }
  if (tid == 0) off[n] = base[256];
}

__global__ __launch_bounds__(256) void k_fill(const int* __restrict__ src, const int* __restrict__ dst,
                       const int* __restrict__ ety, const float* __restrict__ ew,
                       const int* __restrict__ off, int* __restrict__ cur,
                       int* __restrict__ csrc, int* __restrict__ cet, float* __restrict__ cw, int E){
  int e = blockIdx.x * 256 + threadIdx.x;
  if (e < E){
    int d = dst[e];
    int p = atomicAdd(&cur[d], 1);
    int i = off[d] + p;
    csrc[i] = src[e];
    cet[i]  = ety[e];
    cw[i]   = ew[e];
  }
}

// ---------------- weight prep: W[K][256] f32 -> Bp hi/lo bf16, layout [kt][n][32kk] ----------------
__global__ __launch_bounds__(64) void k_prep(const float* __restrict__ W, unsigned short* __restrict__ Bp, int K){
  int kt = blockIdx.x;
  int n  = blockIdx.y * 64 + threadIdx.x;
  unsigned short hi[32], lo[32];
#pragma unroll
  for (int kk = 0; kk < 32; ++kk){
    float v = W[(size_t)(kt * 32 + kk) * 256 + n];   // coalesced over n
    unsigned short h = bfhi(v);
    hi[kk] = h;
    lo[kk] = bfhi(v - bf2f(h));
  }
  size_t plane = (size_t)(K >> 5) * 256 * 32;
  size_t b = ((size_t)kt * 256 + n) * 32;
#pragma unroll
  for (int kk = 0; kk < 32; ++kk){
    Bp[b + kk]         = hi[kk];
    Bp[plane + b + kk] = lo[kk];
  }
}

// ---------------- split-bf16 MFMA GEMM: C[M][256] = A[M][K] @ B ----------------
// A: f32 (PERM applies xc permutation/scale, K fixed 896). B: pre-split Bp.
// BM=64, BN=128, BK=32. 4 waves: (wm,wn) in 2x2, each wave 32 rows x 64 cols = 2x4 frags.
template<bool PERM, bool EPI>
__global__ __launch_bounds__(256) void k_mm(
    const float* __restrict__ A, const unsigned short* __restrict__ Bp,
    const float* __restrict__ bias, float* __restrict__ C,
    int M, int K)
{
  __shared__ unsigned short Ah[64 * 40];
  __shared__ unsigned short Al[64 * 40];
  __shared__ unsigned short Bh[128 * 40];
  __shared__ unsigned short Bl[128 * 40];

  const int tid  = threadIdx.x;
  const int lane = tid & 63;
  const int wv   = tid >> 6;
  const int wm   = wv >> 1;
  const int wn   = wv & 1;
  const int l15  = lane & 15;
  const int kg   = lane >> 4;
  const int m0   = blockIdx.x * 64;
  const int n0   = blockIdx.y * 128;

  const size_t planeB = (size_t)(K >> 5) * 256 * 32;

  f4v acc[2][4];
#pragma unroll
  for (int f = 0; f < 2; ++f)
#pragma unroll
    for (int g = 0; g < 4; ++g)
#pragma unroll
      for (int r = 0; r < 4; ++r) acc[f][g][r] = 0.f;

  const int arow = tid >> 2;          // 0..63
  const int akk  = (tid & 3) * 8;     // 0,8,16,24
  const int gr   = m0 + arow;
  const int bn   = tid >> 1;          // 0..127
  const int bk0  = (tid & 1) * 16;    // 0,16

  const int KT = K >> 5;
  for (int kt = 0; kt < KT; ++kt){
    const int k0 = kt * 32;
    // ---- A stage: f32 load -> hi/lo split -> LDS ----
    {
      float av[8];
      if (gr < M){
        if constexpr (PERM){
          int c = k0 + akk;          // 8-chunks never straddle c=128
          const float* sp; float sc;
          if (c < 128){ sp = A + (size_t)gr * 896 + (768 + c); sc = 1.f; }
          else        { sp = A + (size_t)gr * 896 + (c - 128); sc = 3.f; }
          float4 f0 = *(const float4*)sp;
          float4 f1 = *(const float4*)(sp + 4);
          av[0]=f0.x*sc; av[1]=f0.y*sc; av[2]=f0.z*sc; av[3]=f0.w*sc;
          av[4]=f1.x*sc; av[5]=f1.y*sc; av[6]=f1.z*sc; av[7]=f1.w*sc;
        } else {
          const float* sp = A + (size_t)gr * K + k0 + akk;
          float4 f0 = *(const float4*)sp;
          float4 f1 = *(const float4*)(sp + 4);
          av[0]=f0.x; av[1]=f0.y; av[2]=f0.z; av[3]=f0.w;
          av[4]=f1.x; av[5]=f1.y; av[6]=f1.z; av[7]=f1.w;
        }
      } else {
#pragma unroll
        for (int j = 0; j < 8; ++j) av[j] = 0.f;
      }
      s8v hv, lv;
#pragma unroll
      for (int j = 0; j < 8; ++j){
        unsigned short h = bfhi(av[j]);
        hv[j] = (short)h;
        lv[j] = (short)bfhi(av[j] - bf2f(h));
      }
      *(s8v*)&Ah[arow * 40 + akk] = hv;
      *(s8v*)&Al[arow * 40 + akk] = lv;
    }
    // ---- B stage: pre-split bf16, contiguous copy -> LDS ----
    {
      const unsigned short* s = Bp + ((size_t)kt * 256 + n0 + bn) * 32 + bk0;
      s8v b0 = *(const s8v*)s;
      s8v b1 = *(const s8v*)(s + 8);
      *(s8v*)&Bh[bn * 40 + bk0]     = b0;
      *(s8v*)&Bh[bn * 40 + bk0 + 8] = b1;
      const unsigned short* sl = s + planeB;
      s8v c0v = *(const s8v*)sl;
      s8v c1v = *(const s8v*)(sl + 8);
      *(s8v*)&Bl[bn * 40 + bk0]     = c0v;
      *(s8v*)&Bl[bn * 40 + bk0 + 8] = c1v;
    }
    __syncthreads();
    // ---- fragments + MFMA ----
    s8v ah[2], al[2], bh[4], bl[4];
#pragma unroll
    for (int f = 0; f < 2; ++f){
      int row = wm * 32 + f * 16 + l15;
      ah[f] = *(const s8v*)&Ah[row * 40 + kg * 8];
      al[f] = *(const s8v*)&Al[row * 40 + kg * 8];
    }
#pragma unroll
    for (int g = 0; g < 4; ++g){
      int col = wn * 64 + g * 16 + l15;
      bh[g] = *(const s8v*)&Bh[col * 40 + kg * 8];
      bl[g] = *(const s8v*)&Bl[col * 40 + kg * 8];
    }
#pragma unroll
    for (int f = 0; f < 2; ++f)
#pragma unroll
      for (int g = 0; g < 4; ++g){
        acc[f][g] = __builtin_amdgcn_mfma_f32_16x16x32_bf16(ah[f], bh[g], acc[f][g], 0, 0, 0);
        acc[f][g] = __builtin_amdgcn_mfma_f32_16x16x32_bf16(ah[f], bl[g], acc[f][g], 0, 0, 0);
        acc[f][g] = __builtin_amdgcn_mfma_f32_16x16x32_bf16(al[f], bh[g], acc[f][g], 0, 0, 0);
      }
    __syncthreads();
  }

  // ---- epilogue: D layout col=lane&15, row=(lane>>4)*4+reg (m89-verified) ----
#pragma unroll
  for (int f = 0; f < 2; ++f){
#pragma unroll
    for (int g = 0; g < 4; ++g){
      int col = n0 + wn * 64 + g * 16 + l15;
      float bb = EPI ? bias[col] : 0.f;
#pragma unroll
      for (int r = 0; r < 4; ++r){
        int row = m0 + wm * 32 + f * 16 + kg * 4 + r;
        if (row < M){
          float v = acc[f][g][r];
          if constexpr (EPI) v = fmaxf(v + bb, 0.f);
          C[(size_t)row * 256 + col] = v;
        }
      }
    }
  }
}

// ---------------- attention head projections from xh ----------------
__global__ __launch_bounds__(256) void k_att(
    const float* __restrict__ xh, const float* __restrict__ attS, const float* __restrict__ attD,
    float* __restrict__ aS, float* __restrict__ aD, int N)
{
  int n = blockIdx.x * 4 + (threadIdx.x >> 6);
  if (n >= N) return;
  int lane = threadIdx.x & 63;
  int c0 = lane * 4;
  float4 xv = *(const float4*)&xh[(size_t)n * 256 + c0];
  float4 sv = *(const float4*)&attS[c0];
  float4 dv = *(const float4*)&attD[c0];
  float ps = xv.x*sv.x + xv.y*sv.y + xv.z*sv.z + xv.w*sv.w;
  float pd = xv.x*dv.x + xv.y*dv.y + xv.z*dv.z + xv.w*dv.w;
#pragma unroll
  for (int mm = 1; mm < 16; mm <<= 1){
    ps += __shfl_xor(ps, mm, 64);
    pd += __shfl_xor(pd, mm, 64);
  }
  if ((lane & 15) == 0){
    int head = lane >> 4;
    aS[(size_t)n * 4 + head] = ps;
    aD[(size_t)n * 4 + head] = pd;
  }
}

// ---------------- first aggregation: h1 = h0 + sum_e (h0[src] + rel[et]*w) ----------------
__global__ __launch_bounds__(256) void k_agg(
    const float* __restrict__ h0, const int* __restrict__ off,
    const int* __restrict__ csrc, const int* __restrict__ cet, const float* __restrict__ cw,
    const float* __restrict__ rel, float* __restrict__ h1, int N)
{
  int n = blockIdx.x * 4 + (threadIdx.x >> 6);
  if (n >= N) return;
  int lane = threadIdx.x & 63;
  int c0 = lane * 4;
  float4 acc = *(const float4*)&h0[(size_t)n * 256 + c0];
  int s0 = off[n], s1 = off[n + 1];
  for (int e = s0; e < s1; ++e){
    int s   = csrc[e];
    int t   = cet[e];
    float wg = cw[e];
    float4 hv = *(const float4*)&h0[(size_t)s * 256 + c0];
    float4 rv = *(const float4*)&rel[(size_t)t * 256 + c0];
    acc.x += hv.x + rv.x * wg;
    acc.y += hv.y + rv.y * wg;
    acc.z += hv.z + rv.z * wg;
    acc.w += hv.w + rv.w * wg;
  }
  *(float4*)&h1[(size_t)n * 256 + c0] = acc;
}

// ---------------- GAT edge softmax + aggregate (self-loop included) ----------------
__global__ __launch_bounds__(256) void k_gat(
    const float* __restrict__ xh, const float* __restrict__ aS, const float* __restrict__ aD,
    const int* __restrict__ off, const int* __restrict__ csrc,
    const float* __restrict__ bias, float* __restrict__ hout, int N)
{
  int n = blockIdx.x * 4 + (threadIdx.x >> 6);
  if (n >= N) return;
  int lane = threadIdx.x & 63;
  int head = lane >> 4;
  int c0 = lane * 4;
  int s0 = off[n], s1 = off[n + 1];

  float ad0, ad1, ad2, ad3;
  { float4 t = *(const float4*)&aD[(size_t)n * 4]; ad0 = t.x; ad1 = t.y; ad2 = t.z; ad3 = t.w; }
  float q0, q1, q2, q3;  // running max per head (init with self-loop)
  { float4 t = *(const float4*)&aS[(size_t)n * 4];
    q0 = lrelu(t.x + ad0); q1 = lrelu(t.y + ad1); q2 = lrelu(t.z + ad2); q3 = lrelu(t.w + ad3); }

  for (int base = s0; base < s1; base += 64){
    int e = base + lane;
    if (e < s1){
      int s = csrc[e];
      float4 av = *(const float4*)&aS[(size_t)s * 4];
      q0 = fmaxf(q0, lrelu(av.x + ad0));
      q1 = fmaxf(q1, lrelu(av.y + ad1));
      q2 = fmaxf(q2, lrelu(av.z + ad2));
      q3 = fmaxf(q3, lrelu(av.w + ad3));
    }
  }
#pragma unroll
  for (int mm = 1; mm < 64; mm <<= 1){
    q0 = fmaxf(q0, __shfl_xor(q0, mm, 64));
    q1 = fmaxf(q1, __shfl_xor(q1, mm, 64));
    q2 = fmaxf(q2, __shfl_xor(q2, mm, 64));
    q3 = fmaxf(q3, __shfl_xor(q3, mm, 64));
  }
  float adh = head == 0 ? ad0 : (head == 1 ? ad1 : (head == 2 ? ad2 : ad3));
  float mh  = head == 0 ? q0  : (head == 1 ? q1  : (head == 2 ? q2  : q3));

  float ash = aS[(size_t)n * 4 + head];
  float ex = __expf(lrelu(ash + adh) - mh);
  float den = ex;
  float4 xv = *(const float4*)&xh[(size_t)n * 256 + c0];
  float4 acc;
  acc.x = ex * xv.x; acc.y = ex * xv.y; acc.z = ex * xv.z; acc.w = ex * xv.w;
  for (int e = s0; e < s1; ++e){
    int s = csrc[e];
    float a  = aS[(size_t)s * 4 + head];
    float e2 = __expf(lrelu(a + adh) - mh);
    den += e2;
    float4 x2 = *(const float4*)&xh[(size_t)s * 256 + c0];
    acc.x = fmaf(e2, x2.x, acc.x);
    acc.y = fmaf(e2, x2.y, acc.y);
    acc.z = fmaf(e2, x2.z, acc.z);
    acc.w = fmaf(e2, x2.w, acc.w);
  }
  float inv = 1.f / den;
  float4 bb = *(const float4*)&bias[c0];
  float4 o;
  o.x = acc.x * inv + bb.x;
  o.y = acc.y * inv + bb.y;
  o.z = acc.z * inv + bb.z;
  o.w = acc.w * inv + bb.w;
  *(float4*)&hout[(size_t)n * 256 + c0] = o;
}

// ---------------- final score ----------------
__global__ __launch_bounds__(256) void k_score(
    const float* __restrict__ h, const float* __restrict__ Wo, const float* __restrict__ bo,
    float* __restrict__ out, int N)
{
  int n = blockIdx.x * 4 + (threadIdx.x >> 6);
  if (n >= N) return;
  int lane = threadIdx.x & 63;
  int c0 = lane * 4;
  float4 hv = *(const float4*)&h[(size_t)n * 256 + c0];
  float4 wv = *(const float4*)&Wo[c0];
  float p = hv.x * wv.x + hv.y * wv.y + hv.z * wv.z + hv.w * wv.w;
#pragma unroll
  for (int mm = 1; mm < 64; mm <<= 1) p += __shfl_xor(p, mm, 64);
  if (lane == 0) out[n] = p + bo[0];
}

extern "C" void kernel_launch(void* const* d_in, const int* in_sizes, int n_in,
                              void* d_out, int out_size, void* d_ws, size_t ws_size,
                              hipStream_t stream)
{
  const float* x   = (const float*)d_in[0];
  const int*   ei  = (const int*)  d_in[1];
  const int*   ety = (const int*)  d_in[2];
  const float* ew  = (const float*)d_in[3];
  const float* rel = (const float*)d_in[4];
  const float* Wp  = (const float*)d_in[5];
  const float* bp  = (const float*)d_in[6];
  const float* W1  = (const float*)d_in[7];
  const float* as1 = (const float*)d_in[8];
  const float* ad1 = (const float*)d_in[9];
  const float* b1  = (const float*)d_in[10];
  const float* W2  = (const float*)d_in[11];
  const float* as2 = (const float*)d_in[12];
  const float* ad2 = (const float*)d_in[13];
  const float* b2  = (const float*)d_in[14];
  const float* Wo  = (const float*)d_in[15];
  const float* bo  = (const float*)d_in[16];
  float* out = (float*)d_out;

  const int N = N_NODES, E = E_EDGES;
  char* w = (char*)d_ws;
  size_t o = 0;
  auto alloc = [&](size_t bytes) -> char* {
    char* p = w + o;
    o = (o + bytes + 255) & ~(size_t)255;
    return p;
  };
  float* h0  = (float*)alloc((size_t)N * 256 * 4);
  float* h1  = (float*)alloc((size_t)N * 256 * 4);
  float* xh  = (float*)alloc((size_t)N * 256 * 4);
  float* aS  = (float*)alloc((size_t)N * 4 * 4);
  float* aD  = (float*)alloc((size_t)N * 4 * 4);
  int* deg   = (int*)alloc((size_t)N * 4);
  int* offs  = (int*)alloc((size_t)(N + 1) * 4);
  int* cur   = (int*)alloc((size_t)N * 4);
  int* csrc  = (int*)alloc((size_t)E * 4);
  int* cet   = (int*)alloc((size_t)E * 4);
  float* cw  = (float*)alloc((size_t)E * 4);
  unsigned short* BpP = (unsigned short*)alloc((size_t)2 * 896 * 256 * 2);
  unsigned short* Bp1 = (unsigned short*)alloc((size_t)2 * 256 * 256 * 2);
  unsigned short* Bp2 = (unsigned short*)alloc((size_t)2 * 256 * 256 * 2);

  const int* srcp = ei;
  const int* dstp = ei + E;

  hipMemsetAsync(deg, 0, (size_t)N * 4, stream);
  k_count<<<(E + 255) / 256, 256, 0, stream>>>(dstp, deg, E);
  k_scan<<<1, 256, 0, stream>>>(deg, offs, cur, N);
  k_fill<<<(E + 255) / 256, 256, 0, stream>>>(srcp, dstp, ety, ew, offs, cur, csrc, cet, cw, E);

  // weight pre-split
  k_prep<<<dim3(896 / 32, 4), 64, 0, stream>>>(Wp, BpP, 896);
  k_prep<<<dim3(256 / 32, 4), 64, 0, stream>>>(W1, Bp1, 256);
  k_prep<<<dim3(256 / 32, 4), 64, 0, stream>>>(W2, Bp2, 256);

  dim3 ggrid((N + 63) / 64, 2);
  int nblk = (N + 3) / 4;

  // h0 = relu(xc @ Wp + bp)
  k_mm<true, true><<<ggrid, 256, 0, stream>>>(x, BpP, bp, h0, N, 896);
  // h1 = h0 + sum_in(h0[src] + rel*w)
  k_agg<<<nblk, 256, 0, stream>>>(h0, offs, csrc, cet, cw, rel, h1, N);
  // GAT layer 1
  k_mm<false, false><<<ggrid, 256, 0, stream>>>(h1, Bp1, nullptr, xh, N, 256);
  k_att<<<nblk, 256, 0, stream>>>(xh, as1, ad1, aS, aD, N);
  k_gat<<<nblk, 256, 0, stream>>>(xh, aS, aD, offs, csrc, b1, h1, N);
  // GAT layer 2
  k_mm<false, false><<<ggrid, 256, 0, stream>>>(h1, Bp2, nullptr, xh, N, 256);
  k_att<<<nblk, 256, 0, stream>>>(xh, as2, ad2, aS, aD, N);
  k_gat<<<nblk, 256, 0, stream>>>(xh, aS, aD, offs, csrc, b2, h1, N);
  // score
  k_score<<<nblk, 256, 0, stream>>>(h1, Wo, bo, out, N);
}